// Round 13
// baseline (42839.667 us; speedup 1.0000x reference)
//
#include <hip/hip_runtime.h>

#define DD 1024        // hidden size
#define TT 8192        // sequence length
#define NBLK 128       // grid blocks == barrier participants
#define NTHR 512       // 8 waves per block
#define RPB 8          // rows per block (one per wave)
#define WLDS (RPB * 4 * DD)            // 32768 floats = 128 KB weights
#define LDSB ((WLDS + 4 * DD) * 4)     // + 16 KB dbuf SoA stage = 144 KB

typedef unsigned long long u64;

__device__ __forceinline__ float fast_sigmoid(float x) {
  x = fminf(fmaxf(x, -30.0f), 30.0f);
  return 1.0f / (1.0f + __expf(-x));
}

__device__ __forceinline__ float fast_tanh(float x) {
  x = fminf(fmaxf(x, -15.0f), 15.0f);
  float e = __expf(2.0f * x);
  return (e - 1.0f) / (e + 1.0f);
}

__device__ __forceinline__ u64 ld_cp(const u64* p) {
  return __hip_atomic_load(p, __ATOMIC_RELAXED, __HIP_MEMORY_SCOPE_AGENT);
}

// Persistent LSTM. 128KB LDS weights + 16KB dbuf SoA hc stage.
// R13 = R12 (23.3-24.1ms floor: detect RTT + fetch RTT serial) + speculative
// single-RTT fast path:
//  - state word per row: {u16 tag=t+1 | bf16 c | f32 h} in ONE 8B relaxed
//    agent atomic — self-certifying (tag+values atomically consistent).
//  - consumer wave0 SPECULATIVELY fetches all 16 words/lane first. If every
//    tag == t: done in ONE RTT (detect eliminated). Else: fall back to the
//    R12 cheap flag-spin (u64 loads: 1/lane/round over 8 hot lines), then
//    re-fetch only stale words (flags certify freshness — producer drains
//    vmcnt at the pre-flag barrier, so post-flag loads see final data).
//  - R11's lesson respected: the spec fetch is ONE bounded extra round on
//    miss, never an unbounded data-spin.
//  - payload halved to 8KB (bf16 c): fewer same-line IF$ requests; h stays
//    fp32 (dominant path exact). blockIdx-rotated load order spreads the
//    128-consumer same-line storm.
//  - workspace (flags+hcw) memset per call: kills cross-call tag aliasing
//    (leftover tag 8191 would alias step-8191 wants).
__global__ __launch_bounds__(NTHR, 1) void lstm_seq(
    const float* __restrict__ X,      // [T, D]
    const float* __restrict__ enc_h,  // [D]
    const float* __restrict__ enc_c,  // [D]
    const float* __restrict__ Wf, const float* __restrict__ bf_,
    const float* __restrict__ Wi, const float* __restrict__ bi_,
    const float* __restrict__ Wc, const float* __restrict__ bc_,
    const float* __restrict__ Wo, const float* __restrict__ bo_,
    float* __restrict__ out,          // [T, D] h_t rows
    u64* __restrict__ hcw,            // [2][D] tagged {tag|c_bf16|h_f32}
    unsigned* __restrict__ flags)     // [NBLK] packed (512 B)
{
  extern __shared__ float lds[];      // weights | hst[2][D] | cst[2][D]
  const int wv   = threadIdx.x >> 6;  // wave = local row 0..7
  const int lane = threadIdx.x & 63;
  const int j    = blockIdx.x * RPB + wv;

  // ---- stage h-part weights into LDS (once); gate order f,i,o,C ----
  for (int idx = threadIdx.x; idx < RPB * 4 * 256; idx += NTHR) {
    const int r = idx >> 10, g = (idx >> 8) & 3, q = idx & 255;
    const int row = blockIdx.x * RPB + r;
    const float* ws = (g == 0) ? Wf : (g == 1) ? Wi : (g == 2) ? Wo : Wc;
    *(float4*)&lds[idx * 4] = *(const float4*)(ws + (size_t)row * 2048 + q * 4);
  }

  // ---- per-lane constant weights in registers (x-parts + c-part) ----
  float wxf[16], wxi[16], wxo[16], wcc[16];
#pragma unroll
  for (int kb = 0; kb < 4; ++kb) {
    const int k = 1024 + kb * 256 + lane * 4;
    *(float4*)&wxf[kb*4] = *(const float4*)(Wf + (size_t)j * 2048 + k);
    *(float4*)&wxi[kb*4] = *(const float4*)(Wi + (size_t)j * 2048 + k);
    *(float4*)&wxo[kb*4] = *(const float4*)(Wo + (size_t)j * 2048 + k);
    *(float4*)&wcc[kb*4] = *(const float4*)(Wc + (size_t)j * 2048 + k);
  }
  const float Bf = bf_[j], Bi = bi_[j], Bc = bc_[j], Bo = bo_[j];
  const float* lw = lds + wv * 4096;       // this wave's [4][1024] h-weights
  float* hst = lds + WLDS;                 // [2][1024] staged h (SoA)
  float* cst = lds + WLDS + 2 * DD;        // [2][1024] staged c (SoA)

  float cj = enc_c[j];  // register carry of this row's cell state (fp32 exact)

  __syncthreads();

  // x_0 preload; thereafter x_{t+1} is prefetched a full step ahead
  float4 xc0, xc1, xc2, xc3;
  {
    const float* xq = X + lane * 4;
    xc0 = *(const float4*)(xq);       xc1 = *(const float4*)(xq + 256);
    xc2 = *(const float4*)(xq + 512); xc3 = *(const float4*)(xq + 768);
  }

  const int rot = blockIdx.x & 15;  // fetch-order rotation (spread line storm)

  for (int t = 0; t < TT; ++t) {
    // issue next-step x loads (HBM latency hides under this whole step)
    float4 xn0, xn1, xn2, xn3;
    {
      const size_t tn = (t + 1 < TT) ? (size_t)(t + 1) : (size_t)t;
      const float* xq = X + tn * DD + lane * 4;
      xn0 = *(const float4*)(xq);       xn1 = *(const float4*)(xq + 256);
      xn2 = *(const float4*)(xq + 512); xn3 = *(const float4*)(xq + 768);
    }

    // x-part MACs (barrier-independent; biases added post-reduce — R3 lesson)
    float aF = 0.0f, aI = 0.0f, aO = 0.0f, aC = 0.0f;
#pragma unroll
    for (int kb = 0; kb < 4; ++kb) {
      const float4 xv = (kb==0)?xc0:(kb==1)?xc1:(kb==2)?xc2:xc3;
      const int b = kb * 4;
      aF += wxf[b]*xv.x + wxf[b+1]*xv.y + wxf[b+2]*xv.z + wxf[b+3]*xv.w;
      aI += wxi[b]*xv.x + wxi[b+1]*xv.y + wxi[b+2]*xv.z + wxi[b+3]*xv.w;
      aO += wxo[b]*xv.x + wxo[b+1]*xv.y + wxo[b+2]*xv.z + wxo[b+3]*xv.w;
    }

    const int rp = (t - 1) & 1;  // ring slot produced by step t-1

    if (t > 0) {
      if (wv == 0) {  // wave 0: speculative one-shot fetch of tagged words
        const unsigned want = (unsigned)t;   // step t-1 data carries tag t
        const u64* src = hcw + (size_t)rp * DD + lane;
        u64 raw[16];
#pragma unroll
        for (int q = 0; q < 16; ++q) {
          const int qr = (q + rot) & 15;
          raw[qr] = ld_cp(src + qr * 64);
        }
        bool ok = true;
#pragma unroll
        for (int q = 0; q < 16; ++q) ok &= ((unsigned)(raw[q] >> 48) == want);
        if (!__all(ok)) {
          // fallback: cheap flag spin (1 u64 load/lane/round, 8 hot lines)
          const u64* fl = (const u64*)flags;
          for (;;) {
            u64 f = __hip_atomic_load(&fl[lane], __ATOMIC_RELAXED,
                                      __HIP_MEMORY_SCOPE_AGENT);
            if (__all(((unsigned)f >= want) & ((unsigned)(f >> 32) >= want)))
              break;
          }
          // flags certify data at IF$ — one refetch of stale words suffices
#pragma unroll
          for (int q = 0; q < 16; ++q) {
            if ((unsigned)(raw[q] >> 48) != want) raw[q] = ld_cp(src + q * 64);
          }
        }
        // unpack + SoA stage (stride-1 4B writes — conflict-free)
#pragma unroll
        for (int q = 0; q < 16; ++q) {
          hst[rp * DD + q * 64 + lane] = __uint_as_float((unsigned)raw[q]);
          cst[rp * DD + q * 64 + lane] =
              __uint_as_float(((unsigned)(raw[q] >> 32) & 0xFFFFu) << 16);
        }
      }
      __syncthreads();  // stage visible to all 8 waves

      // MACs from SoA stage: contiguous b128 reads, conflict-free
#pragma unroll
      for (int kb = 0; kb < 4; ++kb) {
        const int o = kb * 256 + lane * 4;
        const float4 hv = *(const float4*)&hst[rp * DD + o];
        const float4 cc = *(const float4*)&cst[rp * DD + o];
        const float4 wF = *(const float4*)&lw[o];
        const float4 wI = *(const float4*)&lw[1024 + o];
        const float4 wO = *(const float4*)&lw[2048 + o];
        const float4 wC = *(const float4*)&lw[3072 + o];
        const int b = kb * 4;
        aF += wF.x*hv.x + wF.y*hv.y + wF.z*hv.z + wF.w*hv.w;
        aI += wI.x*hv.x + wI.y*hv.y + wI.z*hv.z + wI.w*hv.w;
        aO += wO.x*hv.x + wO.y*hv.y + wO.z*hv.z + wO.w*hv.w;
        aC += wC.x*hv.x + wC.y*hv.y + wC.z*hv.z + wC.w*hv.w;
        aC += wcc[b]*cc.x + wcc[b+1]*cc.y + wcc[b+2]*cc.z + wcc[b+3]*cc.w;
      }
    } else {
      // t == 0: initial state straight from inputs (plain loads)
      const float* hp = enc_h + lane * 4;
      const float* cp = enc_c + lane * 4;
#pragma unroll
      for (int kb = 0; kb < 4; ++kb) {
        const int o = kb * 256 + lane * 4;
        const float4 hv = *(const float4*)(hp + kb * 256);
        const float4 cc = *(const float4*)(cp + kb * 256);
        const float4 wF = *(const float4*)&lw[o];
        const float4 wI = *(const float4*)&lw[1024 + o];
        const float4 wO = *(const float4*)&lw[2048 + o];
        const float4 wC = *(const float4*)&lw[3072 + o];
        const int b = kb * 4;
        aF += wF.x*hv.x + wF.y*hv.y + wF.z*hv.z + wF.w*hv.w;
        aI += wI.x*hv.x + wI.y*hv.y + wI.z*hv.z + wI.w*hv.w;
        aO += wO.x*hv.x + wO.y*hv.y + wO.z*hv.z + wO.w*hv.w;
        aC += wC.x*hv.x + wC.y*hv.y + wC.z*hv.z + wC.w*hv.w;
        aC += wcc[b]*cc.x + wcc[b+1]*cc.y + wcc[b+2]*cc.z + wcc[b+3]*cc.w;
      }
    }

#pragma unroll
    for (int m = 32; m >= 1; m >>= 1) {
      aF += __shfl_xor(aF, m, 64);
      aI += __shfl_xor(aI, m, 64);
      aO += __shfl_xor(aO, m, 64);
      aC += __shfl_xor(aC, m, 64);
    }

    // biases added exactly once, post-reduction
    const float fg = fast_sigmoid(aF + Bf);
    const float ig = fast_sigmoid(aI + Bi);
    const float og = fast_sigmoid(aO + Bo);
    const float ct = fast_tanh(aC + Bc);
    const float cn = fg * cj + ig * ct;
    const float hn = og * fast_tanh(cn);
    cj = cn;

    if (lane == 0) {
      out[(size_t)t * DD + j] = hn;  // fp32 output, exact
      // pack {u16 tag=t+1 | bf16 c (RTN) | f32 h} into one 8B word
      const unsigned hb = __float_as_uint(hn);
      const unsigned cb = __float_as_uint(cn);
      const unsigned cbf = (cb + 0x7FFFu + ((cb >> 16) & 1u)) >> 16;  // RTN-even
      const u64 w = ((u64)(unsigned)(t + 1) << 48) |
                    ((u64)(cbf & 0xFFFFu) << 32) | (u64)hb;
      __hip_atomic_store(&hcw[(size_t)(t & 1) * DD + j], w,
                         __ATOMIC_RELAXED, __HIP_MEMORY_SCOPE_AGENT);
    }
    __syncthreads();  // drains each wave's vmcnt: hc stores ack'd at IF$
    if (threadIdx.x == 0) {
      // relaxed: ordering provided by the pre-barrier vmcnt drains
      __hip_atomic_store(&flags[blockIdx.x], (unsigned)(t + 1),
                         __ATOMIC_RELAXED, __HIP_MEMORY_SCOPE_AGENT);
    }
    xc0 = xn0; xc1 = xn1; xc2 = xn2; xc3 = xn3;
  }
}

extern "C" void kernel_launch(void* const* d_in, const int* in_sizes, int n_in,
                              void* d_out, int out_size, void* d_ws, size_t ws_size,
                              hipStream_t stream) {
  const float* X    = (const float*)d_in[0];
  const float* eh   = (const float*)d_in[1];
  const float* ec   = (const float*)d_in[2];
  const float* Wf   = (const float*)d_in[3];
  const float* bf_  = (const float*)d_in[4];
  const float* Wi   = (const float*)d_in[5];
  const float* bi_  = (const float*)d_in[6];
  const float* Wc   = (const float*)d_in[7];
  const float* bc_  = (const float*)d_in[8];
  const float* Wo   = (const float*)d_in[9];
  const float* bo_  = (const float*)d_in[10];
  float* out = (float*)d_out;

  unsigned* flags = (unsigned*)d_ws;                // 512 B
  u64* hcw = (u64*)((char*)d_ws + 1024);            // [2][1024] tagged (16 KB)

  // zero flags AND tagged words: stale tags from a previous call would alias
  // late-step wants (e.g. leftover tag 8191 == step-8191's want)
  hipMemsetAsync(d_ws, 0, 1024 + 16384, stream);

  hipFuncSetAttribute((const void*)lstm_seq,
                      hipFuncAttributeMaxDynamicSharedMemorySize, LDSB);

  void* args[] = {(void*)&X, (void*)&eh, (void*)&ec,
                  (void*)&Wf, (void*)&bf_, (void*)&Wi, (void*)&bi_,
                  (void*)&Wc, (void*)&bc_, (void*)&Wo, (void*)&bo_,
                  (void*)&out, (void*)&hcw, (void*)&flags};
  hipError_t e = hipLaunchCooperativeKernel((const void*)lstm_seq,
                                            dim3(NBLK), dim3(NTHR),
                                            args, LDSB, stream);
  if (e != hipSuccess) {
    // plain-launch fallback: 128 blocks x 144KB LDS => 1 block/CU, co-resident
    lstm_seq<<<dim3(NBLK), dim3(NTHR), LDSB, stream>>>(
        X, eh, ec, Wf, bf_, Wi, bi_, Wc, bc_, Wo, bo_, out, hcw, flags);
  }
}

// Round 14
// 24754.419 us; speedup vs baseline: 1.7306x; 1.7306x over previous
//
#include <hip/hip_runtime.h>

#define DD 1024        // hidden size
#define TT 8192        // sequence length
#define NBLK 128       // grid blocks == barrier participants
#define NTHR 512       // 8 waves per block
#define RPB 8          // rows per block (one per wave)
#define WLDS (RPB * 4 * DD)            // 32768 floats = 128 KB weights
#define LDSB ((WLDS + 4 * DD) * 4)     // + 16 KB dbuf SoA stage = 144 KB

typedef unsigned long long u64;

__device__ __forceinline__ float fast_sigmoid(float x) {
  x = fminf(fmaxf(x, -30.0f), 30.0f);
  return 1.0f / (1.0f + __expf(-x));
}

__device__ __forceinline__ float fast_tanh(float x) {
  x = fminf(fmaxf(x, -15.0f), 15.0f);
  float e = __expf(2.0f * x);
  return (e - 1.0f) / (e + 1.0f);
}

union HC { u64 u; float2 f; };

__device__ __forceinline__ u64 ld_cp(const u64* p) {
  return __hip_atomic_load(p, __ATOMIC_RELAXED, __HIP_MEMORY_SCOPE_AGENT);
}

// Persistent LSTM. 128KB LDS weights + 16KB dbuf SoA hc stage.
// R14 = R12 (validated floor structure: cheap-flag detect -> one-shot fetch
// -> SoA stage; 24.1ms stable) with two detect-phase micro-opts only:
//  - DOUBLE-PUMPED poll: two flag loads in flight, checked alternately.
//    Detect sampling granularity ~RTT/2 instead of ~RTT.
//  - u64 flag loads: 64 lanes x one 8B load covers all 128 flags (halves
//    poll request count; single 512B hot region).
// Protocol laws (R4..R13): spin on minimal hot lines; fetch bulk exactly
// once, only after certification; spinners <= 1 wave/block; no sleep; no
// speculative/tagged paths (R10/R11/R13 all regressed).
__global__ __launch_bounds__(NTHR, 1) void lstm_seq(
    const float* __restrict__ X,      // [T, D]
    const float* __restrict__ enc_h,  // [D]
    const float* __restrict__ enc_c,  // [D]
    const float* __restrict__ Wf, const float* __restrict__ bf_,
    const float* __restrict__ Wi, const float* __restrict__ bi_,
    const float* __restrict__ Wc, const float* __restrict__ bc_,
    const float* __restrict__ Wo, const float* __restrict__ bo_,
    float* __restrict__ out,          // [T, D] h_t rows
    u64* __restrict__ hcbuf,          // [2][D] ring of packed {h,c}
    unsigned* __restrict__ flags)     // [NBLK] packed (512 B)
{
  extern __shared__ float lds[];      // weights | hst[2][D] | cst[2][D]
  const int wv   = threadIdx.x >> 6;  // wave = local row 0..7
  const int lane = threadIdx.x & 63;
  const int j    = blockIdx.x * RPB + wv;

  // ---- stage h-part weights into LDS (once); gate order f,i,o,C ----
  for (int idx = threadIdx.x; idx < RPB * 4 * 256; idx += NTHR) {
    const int r = idx >> 10, g = (idx >> 8) & 3, q = idx & 255;
    const int row = blockIdx.x * RPB + r;
    const float* ws = (g == 0) ? Wf : (g == 1) ? Wi : (g == 2) ? Wo : Wc;
    *(float4*)&lds[idx * 4] = *(const float4*)(ws + (size_t)row * 2048 + q * 4);
  }

  // ---- per-lane constant weights in registers (x-parts + c-part) ----
  float wxf[16], wxi[16], wxo[16], wcc[16];
#pragma unroll
  for (int kb = 0; kb < 4; ++kb) {
    const int k = 1024 + kb * 256 + lane * 4;
    *(float4*)&wxf[kb*4] = *(const float4*)(Wf + (size_t)j * 2048 + k);
    *(float4*)&wxi[kb*4] = *(const float4*)(Wi + (size_t)j * 2048 + k);
    *(float4*)&wxo[kb*4] = *(const float4*)(Wo + (size_t)j * 2048 + k);
    *(float4*)&wcc[kb*4] = *(const float4*)(Wc + (size_t)j * 2048 + k);
  }
  const float Bf = bf_[j], Bi = bi_[j], Bc = bc_[j], Bo = bo_[j];
  const float* lw = lds + wv * 4096;       // this wave's [4][1024] h-weights
  float* hst = lds + WLDS;                 // [2][1024] staged h (SoA)
  float* cst = lds + WLDS + 2 * DD;        // [2][1024] staged c (SoA)

  float cj = enc_c[j];  // register carry of this row's cell state

  __syncthreads();

  // x_0 preload; thereafter x_{t+1} is prefetched a full step ahead
  float4 xc0, xc1, xc2, xc3;
  {
    const float* xq = X + lane * 4;
    xc0 = *(const float4*)(xq);       xc1 = *(const float4*)(xq + 256);
    xc2 = *(const float4*)(xq + 512); xc3 = *(const float4*)(xq + 768);
  }

  for (int t = 0; t < TT; ++t) {
    // issue next-step x loads (HBM latency hides under this whole step)
    float4 xn0, xn1, xn2, xn3;
    {
      const size_t tn = (t + 1 < TT) ? (size_t)(t + 1) : (size_t)t;
      const float* xq = X + tn * DD + lane * 4;
      xn0 = *(const float4*)(xq);       xn1 = *(const float4*)(xq + 256);
      xn2 = *(const float4*)(xq + 512); xn3 = *(const float4*)(xq + 768);
    }

    // x-part MACs (barrier-independent; biases added post-reduce — R3 lesson)
    float aF = 0.0f, aI = 0.0f, aO = 0.0f, aC = 0.0f;
#pragma unroll
    for (int kb = 0; kb < 4; ++kb) {
      const float4 xv = (kb==0)?xc0:(kb==1)?xc1:(kb==2)?xc2:xc3;
      const int b = kb * 4;
      aF += wxf[b]*xv.x + wxf[b+1]*xv.y + wxf[b+2]*xv.z + wxf[b+3]*xv.w;
      aI += wxi[b]*xv.x + wxi[b+1]*xv.y + wxi[b+2]*xv.z + wxi[b+3]*xv.w;
      aO += wxo[b]*xv.x + wxo[b+1]*xv.y + wxo[b+2]*xv.z + wxo[b+3]*xv.w;
    }

    const int rp = (t - 1) & 1;  // ring slot produced by step t-1

    if (t > 0) {
      if (wv == 0) {  // wave 0: double-pumped poll, then one-shot fetch+stage
        const unsigned tt = (unsigned)t;
        const u64* fl = (const u64*)flags;  // 64 u64 = all 128 flags
        u64 a = ld_cp(fl + lane);           // two loads in flight, checked
        u64 b = ld_cp(fl + lane);           // alternately: sample ~RTT/2
        for (;;) {
          if (__all(((unsigned)a >= tt) & ((unsigned)(a >> 32) >= tt))) break;
          a = ld_cp(fl + lane);
          if (__all(((unsigned)b >= tt) & ((unsigned)(b >> 32) >= tt))) break;
          b = ld_cp(fl + lane);
        }
        // fetch the 1024 {h,c} pairs exactly once: 16x 8B coherence loads
        const u64* src = hcbuf + (size_t)rp * DD + lane;
        u64 raw[16];
#pragma unroll
        for (int q = 0; q < 16; ++q) raw[q] = ld_cp(src + q * 64);
        // SoA stage: 4B stride-1 writes at q*256B + lane*4B — conflict-free
#pragma unroll
        for (int q = 0; q < 16; ++q) {
          HC u; u.u = raw[q];
          hst[rp * DD + q * 64 + lane] = u.f.x;
          cst[rp * DD + q * 64 + lane] = u.f.y;
        }
      }
      __syncthreads();  // stage visible to all 8 waves

      // MACs from SoA stage: contiguous b128 reads, conflict-free
#pragma unroll
      for (int kb = 0; kb < 4; ++kb) {
        const int o = kb * 256 + lane * 4;
        const float4 hv = *(const float4*)&hst[rp * DD + o];
        const float4 cc = *(const float4*)&cst[rp * DD + o];
        const float4 wF = *(const float4*)&lw[o];
        const float4 wI = *(const float4*)&lw[1024 + o];
        const float4 wO = *(const float4*)&lw[2048 + o];
        const float4 wC = *(const float4*)&lw[3072 + o];
        const int b = kb * 4;
        aF += wF.x*hv.x + wF.y*hv.y + wF.z*hv.z + wF.w*hv.w;
        aI += wI.x*hv.x + wI.y*hv.y + wI.z*hv.z + wI.w*hv.w;
        aO += wO.x*hv.x + wO.y*hv.y + wO.z*hv.z + wO.w*hv.w;
        aC += wC.x*hv.x + wC.y*hv.y + wC.z*hv.z + wC.w*hv.w;
        aC += wcc[b]*cc.x + wcc[b+1]*cc.y + wcc[b+2]*cc.z + wcc[b+3]*cc.w;
      }
    } else {
      // t == 0: initial state straight from inputs (plain loads)
      const float* hp = enc_h + lane * 4;
      const float* cp = enc_c + lane * 4;
#pragma unroll
      for (int kb = 0; kb < 4; ++kb) {
        const int o = kb * 256 + lane * 4;
        const float4 hv = *(const float4*)(hp + kb * 256);
        const float4 cc = *(const float4*)(cp + kb * 256);
        const float4 wF = *(const float4*)&lw[o];
        const float4 wI = *(const float4*)&lw[1024 + o];
        const float4 wO = *(const float4*)&lw[2048 + o];
        const float4 wC = *(const float4*)&lw[3072 + o];
        const int b = kb * 4;
        aF += wF.x*hv.x + wF.y*hv.y + wF.z*hv.z + wF.w*hv.w;
        aI += wI.x*hv.x + wI.y*hv.y + wI.z*hv.z + wI.w*hv.w;
        aO += wO.x*hv.x + wO.y*hv.y + wO.z*hv.z + wO.w*hv.w;
        aC += wC.x*hv.x + wC.y*hv.y + wC.z*hv.z + wC.w*hv.w;
        aC += wcc[b]*cc.x + wcc[b+1]*cc.y + wcc[b+2]*cc.z + wcc[b+3]*cc.w;
      }
    }

#pragma unroll
    for (int m = 32; m >= 1; m >>= 1) {
      aF += __shfl_xor(aF, m, 64);
      aI += __shfl_xor(aI, m, 64);
      aO += __shfl_xor(aO, m, 64);
      aC += __shfl_xor(aC, m, 64);
    }

    // biases added exactly once, post-reduction
    const float fg = fast_sigmoid(aF + Bf);
    const float ig = fast_sigmoid(aI + Bi);
    const float og = fast_sigmoid(aO + Bo);
    const float ct = fast_tanh(aC + Bc);
    const float cn = fg * cj + ig * ct;
    const float hn = og * fast_tanh(cn);
    cj = cn;

    if (lane == 0) {
      out[(size_t)t * DD + j] = hn;  // plain store; host reads after kernel end
      HC u; u.f = make_float2(hn, cn);
      __hip_atomic_store(hcbuf + (size_t)(t & 1) * DD + j, u.u,
                         __ATOMIC_RELAXED, __HIP_MEMORY_SCOPE_AGENT);
    }
    __syncthreads();  // each wave drains vmcnt(0): hc stores ack'd at IF$
    if (threadIdx.x == 0) {
      // relaxed: ordering provided by the per-wave vmcnt drain above
      __hip_atomic_store(&flags[blockIdx.x], (unsigned)(t + 1),
                         __ATOMIC_RELAXED, __HIP_MEMORY_SCOPE_AGENT);
    }
    xc0 = xn0; xc1 = xn1; xc2 = xn2; xc3 = xn3;
  }
}

extern "C" void kernel_launch(void* const* d_in, const int* in_sizes, int n_in,
                              void* d_out, int out_size, void* d_ws, size_t ws_size,
                              hipStream_t stream) {
  const float* X    = (const float*)d_in[0];
  const float* eh   = (const float*)d_in[1];
  const float* ec   = (const float*)d_in[2];
  const float* Wf   = (const float*)d_in[3];
  const float* bf_  = (const float*)d_in[4];
  const float* Wi   = (const float*)d_in[5];
  const float* bi_  = (const float*)d_in[6];
  const float* Wc   = (const float*)d_in[7];
  const float* bc_  = (const float*)d_in[8];
  const float* Wo   = (const float*)d_in[9];
  const float* bo_  = (const float*)d_in[10];
  float* out = (float*)d_out;

  unsigned* flags = (unsigned*)d_ws;                      // 512 B
  u64* hcbuf = (u64*)((char*)d_ws + 1024);                // [2][1024] (16 KB)

  hipMemsetAsync(d_ws, 0, 1024, stream);  // flags must start < 1 each call

  hipFuncSetAttribute((const void*)lstm_seq,
                      hipFuncAttributeMaxDynamicSharedMemorySize, LDSB);

  void* args[] = {(void*)&X, (void*)&eh, (void*)&ec,
                  (void*)&Wf, (void*)&bf_, (void*)&Wi, (void*)&bi_,
                  (void*)&Wc, (void*)&bc_, (void*)&Wo, (void*)&bo_,
                  (void*)&out, (void*)&hcbuf, (void*)&flags};
  hipError_t e = hipLaunchCooperativeKernel((const void*)lstm_seq,
                                            dim3(NBLK), dim3(NTHR),
                                            args, LDSB, stream);
  if (e != hipSuccess) {
    // plain-launch fallback: 128 blocks x 144KB LDS => 1 block/CU, co-resident
    lstm_seq<<<dim3(NBLK), dim3(NTHR), LDSB, stream>>>(
        X, eh, ec, Wf, bf_, Wi, bi_, Wc, bc_, Wo, bo_, out, hcbuf, flags);
  }
}